// Round 6
// baseline (264.614 us; speedup 1.0000x reference)
//
#include <hip/hip_runtime.h>
#include <math.h>

constexpr int D = 128;       // in_channels
constexpr int B = 512;       // batch_size (graphs)
constexpr int STEPS = 3;
constexpr int ROWS = 3 * D;            // 384 gate rows
constexpr int NP_IH = (2 * D / 4) * ROWS;  // 64*384 uint2 elems (k-groups of 4)
constexpr int NP_HH = (D / 4) * ROWS;      // 32*384 uint2 elems

__device__ __forceinline__ float sigmoidf_(float x) { return 1.f / (1.f + __expf(-x)); }
// bf16 pair unpack from a uint: low halfword / high halfword -> float (exact)
__device__ __forceinline__ float bflo(unsigned int u) { return __uint_as_float(u << 16); }
__device__ __forceinline__ float bfhi(unsigned int u) { return __uint_as_float(u & 0xffff0000u); }
__device__ __forceinline__ unsigned short f2bf_rn(float f) {
    unsigned int u = __float_as_uint(f);
    u += 0x7fffu + ((u >> 16) & 1u);    // round-to-nearest-even
    return (unsigned short)(u >> 16);
}
__device__ __forceinline__ unsigned int pack2(float a, float b) {
    return (unsigned int)f2bf_rn(a) | ((unsigned int)f2bf_rn(b) << 16);
}

// ---------------------------------------------------------------------------
// K0 (prep): weights fp32 -> bf16, TRANSPOSED+PACKED layout:
//   wih_p[c][t].x = {W[t][4c], W[t][4c+1]}, .y = {W[t][4c+2], W[t][4c+3]}
// with t (row) fastest -> GRU loads are 4-B/lane coalesced (512 B/wave-instr,
// zero L2 line amplification). Also: segment bounds via binary search.
// ---------------------------------------------------------------------------
__global__ __launch_bounds__(256) void k_prep(const float* __restrict__ Wih,
        const float* __restrict__ Whh, const int* __restrict__ batch, int n,
        uint2* __restrict__ wih_p, uint2* __restrict__ whh_p,
        int* __restrict__ seg) {
    int i = blockIdx.x * blockDim.x + threadIdx.x;
    if (i < NP_IH) {
        int c = i / ROWS, t = i - c * ROWS;
        const float* src = Wih + (size_t)t * (2 * D) + 4 * c;
        wih_p[i] = make_uint2(pack2(src[0], src[1]), pack2(src[2], src[3]));
    } else if (i < NP_IH + NP_HH) {
        int j = i - NP_IH;
        int c = j / ROWS, t = j - c * ROWS;
        const float* src = Whh + (size_t)t * D + 4 * c;
        whh_p[j] = make_uint2(pack2(src[0], src[1]), pack2(src[2], src[3]));
    }
    if (i <= B) {
        int lo = 0, hi = n;
        while (lo < hi) { int mid = (lo + hi) >> 1; if (batch[mid] < i) lo = mid + 1; else hi = mid; }
        seg[i] = lo;
    }
}

// ---------------------------------------------------------------------------
// K1 (fused Set2Set): one block per graph, 1024 threads, all 3 steps inside.
// State (h, q_star) in LDS; no global intermediates (recurrence is per-graph).
//   GRU:  threads 0..383 compute gate rows from the transposed/packed bf16
//         weights: per-thread uint2 loads at 4-B lane stride (coalesced),
//         4 parallel fma accumulator chains.
//   Attn: flash-style single pass; each half-wave processes chunks of 4 nodes
//         (independent loads/dots/reduces, one rescale per chunk).
//   Softmax combine across 32 half-waves: parallel butterfly on wave 0.
// __launch_bounds__(1024,8): VGPR<=64 -> 2 blocks/CU = 32 waves/CU.
// ---------------------------------------------------------------------------
__global__ __launch_bounds__(1024, 8) void k_set2set(
        const float* __restrict__ x,
        const uint2* __restrict__ wih_p,
        const uint2* __restrict__ whh_p,
        const float* __restrict__ bih, const float* __restrict__ bhh,
        const int* __restrict__ seg, float* __restrict__ out) {
    __shared__ float s_q[2 * D];          // q_star for this graph: [q | r]
    __shared__ float s_h[D];
    __shared__ float s_gi[3 * D], s_gh[3 * D];
    __shared__ float sm[32], sl[32];
    __shared__ float s_M, s_inv;
    __shared__ float rpart[16][D];        // 8 KB

    const int b = blockIdx.x;
    const int tid = threadIdx.x;
    const int start = seg[b], end = seg[b + 1];
    const int lane32 = tid & 31;
    const int hw = tid >> 5;              // half-wave id 0..31

    if (tid < 2 * D) s_q[tid] = 0.f;
    if (tid < D) s_h[tid] = 0.f;
    __syncthreads();

    for (int step = 0; step < STEPS; ++step) {
        // ---- GRU gate rows: coalesced packed-bf16 weight loads ----
        if (tid < ROWS) {
            const int t = tid;
            float a0 = bih[t], a1 = 0.f, a2 = 0.f, a3 = 0.f;
            const uint2* P = wih_p + t;
#pragma unroll 8
            for (int c = 0; c < (2 * D) / 4; ++c) {   // 64 iters
                uint2 w = P[(size_t)c * ROWS];
                const float* q = &s_q[c * 4];
                a0 = fmaf(bflo(w.x), q[0], a0);
                a1 = fmaf(bfhi(w.x), q[1], a1);
                a2 = fmaf(bflo(w.y), q[2], a2);
                a3 = fmaf(bfhi(w.y), q[3], a3);
            }
            s_gi[t] = (a0 + a1) + (a2 + a3);
            float b0 = bhh[t], b1 = 0.f, b2 = 0.f, b3 = 0.f;
            const uint2* Q = whh_p + t;
#pragma unroll 8
            for (int c = 0; c < D / 4; ++c) {         // 32 iters
                uint2 w = Q[(size_t)c * ROWS];
                const float* hh = &s_h[c * 4];
                b0 = fmaf(bflo(w.x), hh[0], b0);
                b1 = fmaf(bfhi(w.x), hh[1], b1);
                b2 = fmaf(bflo(w.y), hh[2], b2);
                b3 = fmaf(bfhi(w.y), hh[3], b3);
            }
            s_gh[t] = (b0 + b1) + (b2 + b3);
        }
        __syncthreads();
        // ---- GRU epilogue ----
        if (tid < D) {
            const int t = tid;
            float r  = sigmoidf_(s_gi[t] + s_gh[t]);
            float z  = sigmoidf_(s_gi[D + t] + s_gh[D + t]);
            float nn = tanhf(s_gi[2 * D + t] + r * s_gh[2 * D + t]);
            float hn = (1.f - z) * nn + z * s_h[t];
            s_h[t] = hn;
            s_q[t] = hn;                  // q part of q_star
        }
        __syncthreads();

        // ---- flash attention, 4-node chunks per half-wave ----
        const float4 qf = *(const float4*)&s_h[lane32 * 4];
        float m_run = -INFINITY, l_run = 0.f;
        float4 acc = {0.f, 0.f, 0.f, 0.f};
        for (int base = start + hw * 4; base < end; base += 32 * 4) {
            float4 xv0, xv1, xv2, xv3;
            {
                int n0 = base;
                int n1 = (base + 1 < end) ? base + 1 : end - 1;
                int n2 = (base + 2 < end) ? base + 2 : end - 1;
                int n3 = (base + 3 < end) ? base + 3 : end - 1;
                xv0 = ((const float4*)(x + (size_t)n0 * D))[lane32];
                xv1 = ((const float4*)(x + (size_t)n1 * D))[lane32];
                xv2 = ((const float4*)(x + (size_t)n2 * D))[lane32];
                xv3 = ((const float4*)(x + (size_t)n3 * D))[lane32];
            }
            float p0 = fmaf(xv0.x, qf.x, fmaf(xv0.y, qf.y, fmaf(xv0.z, qf.z, xv0.w * qf.w)));
            float p1 = fmaf(xv1.x, qf.x, fmaf(xv1.y, qf.y, fmaf(xv1.z, qf.z, xv1.w * qf.w)));
            float p2 = fmaf(xv2.x, qf.x, fmaf(xv2.y, qf.y, fmaf(xv2.z, qf.z, xv2.w * qf.w)));
            float p3 = fmaf(xv3.x, qf.x, fmaf(xv3.y, qf.y, fmaf(xv3.z, qf.z, xv3.w * qf.w)));
#pragma unroll
            for (int s = 16; s >= 1; s >>= 1) {
                p0 += __shfl_xor(p0, s, 64);
                p1 += __shfl_xor(p1, s, 64);
                p2 += __shfl_xor(p2, s, 64);
                p3 += __shfl_xor(p3, s, 64);
            }
            if (base + 1 >= end) p1 = -INFINITY;
            if (base + 2 >= end) p2 = -INFINITY;
            if (base + 3 >= end) p3 = -INFINITY;

            float cm = fmaxf(fmaxf(p0, p1), fmaxf(p2, p3));
            float nm = fmaxf(m_run, cm);
            float scale = __expf(m_run - nm);   // 0 on first chunk
            float a0 = __expf(p0 - nm);
            float a1 = __expf(p1 - nm);
            float a2 = __expf(p2 - nm);
            float a3 = __expf(p3 - nm);
            l_run = fmaf(l_run, scale, (a0 + a1) + (a2 + a3));
            acc.x = fmaf(acc.x, scale, fmaf(a0, xv0.x, fmaf(a1, xv1.x, fmaf(a2, xv2.x, a3 * xv3.x))));
            acc.y = fmaf(acc.y, scale, fmaf(a0, xv0.y, fmaf(a1, xv1.y, fmaf(a2, xv2.y, a3 * xv3.y))));
            acc.z = fmaf(acc.z, scale, fmaf(a0, xv0.z, fmaf(a1, xv1.z, fmaf(a2, xv2.z, a3 * xv3.z))));
            acc.w = fmaf(acc.w, scale, fmaf(a0, xv0.w, fmaf(a1, xv1.w, fmaf(a2, xv2.w, a3 * xv3.w))));
            m_run = nm;
        }
        if (lane32 == 0) { sm[hw] = m_run; sl[hw] = l_run; }
        __syncthreads();
        // ---- parallel butterfly combine of 32 (m,l) pairs on wave 0 ----
        if (tid < 64) {
            float m = sm[tid & 31], l = sl[tid & 31];
#pragma unroll
            for (int s = 16; s >= 1; s >>= 1) {
                float mo = __shfl_xor(m, s, 64);
                float lo = __shfl_xor(l, s, 64);
                float nm2 = fmaxf(m, mo);
                float t1 = (m  == -INFINITY) ? 0.f : l  * __expf(m  - nm2);
                float t2 = (mo == -INFINITY) ? 0.f : lo * __expf(mo - nm2);
                l = t1 + t2; m = nm2;
            }
            if (tid == 0) { s_M = m; s_inv = 1.f / (l + 1e-16f); }
        }
        __syncthreads();
        // rescale to global max; empty half-wave / empty graph -> exactly 0
        const float fac = (m_run == -INFINITY) ? 0.f : __expf(m_run - s_M);
        acc.x *= fac; acc.y *= fac; acc.z *= fac; acc.w *= fac;
        // fold upper half-wave onto lower within each 64-lane wave
        acc.x += __shfl_down(acc.x, 32, 64);
        acc.y += __shfl_down(acc.y, 32, 64);
        acc.z += __shfl_down(acc.z, 32, 64);
        acc.w += __shfl_down(acc.w, 32, 64);
        const int wave = tid >> 6;        // 0..15
        const int lane64 = tid & 63;
        if (lane64 < 32) ((float4*)rpart[wave])[lane64] = acc;
        __syncthreads();
        if (tid < D) {
            float v = 0.f;
#pragma unroll
            for (int w = 0; w < 16; ++w) v += rpart[w][tid];
            s_q[D + tid] = v * s_inv;     // r part of q_star
        }
        __syncthreads();                  // s_q complete for next GRU / output
    }

    // ---- write q_star row (s_q is exactly [q | r]) ----
    if (tid < 2 * D) out[(size_t)b * (2 * D) + tid] = s_q[tid];
}

// ---------------------------------------------------------------------------
extern "C" void kernel_launch(void* const* d_in, const int* in_sizes, int n_in,
                              void* d_out, int out_size, void* d_ws, size_t ws_size,
                              hipStream_t stream) {
    const float* x    = (const float*)d_in[0];
    const int*   batch= (const int*)d_in[1];
    // d_in[2] = batch_size scalar (fixed at B=512 compile time)
    const float* Wih  = (const float*)d_in[3];
    const float* Whh  = (const float*)d_in[4];
    const float* bih  = (const float*)d_in[5];
    const float* bhh  = (const float*)d_in[6];
    const int n = in_sizes[0] / D;        // 200000

    // workspace: seg (4 KB pad) | wih_p (192 KB, uint2) | whh_p (96 KB, uint2)
    char* ws = (char*)d_ws;
    int* seg = (int*)ws;
    uint2* wih_p = (uint2*)(ws + 4096);
    uint2* whh_p = (uint2*)(ws + 4096 + (size_t)NP_IH * sizeof(uint2));

    const int total = NP_IH + NP_HH;      // 36864 >= B+1, covers seg too
    k_prep<<<(total + 255) / 256, 256, 0, stream>>>(Wih, Whh, batch, n, wih_p, whh_p, seg);
    k_set2set<<<B, 1024, 0, stream>>>(x, wih_p, whh_p, bih, bhh, seg, (float*)d_out);
}